// Round 6
// baseline (1943.318 us; speedup 1.0000x reference)
//
#include <hip/hip_runtime.h>
#include <stdint.h>

#define HW 262144              // 512*512
#define NB 32                  // batch
#define TOPK 4096
#define NTOTAL (NB * HW)       // 8388608

// ---------------- ws layout (bytes) ----------------
// d:       uint32[NTOTAL]            @ 0          (33,554,432)
// mask:    uint8 [NTOTAL]            @ 33554432   ( 8,388,608)
// hist:    uint32[NB][256]           @ 41943040   (    32,768)
// state:   uint32[NB][2] (pfx, rem)  @ 41975808   (       256)
// cnt:     uint32[NB]                @ 41976064   (       128)
// winners: uint64[NB][8192]          @ 41976192   ( 2,097,152)

__device__ __forceinline__ uint32_t rotl32(uint32_t x, int d) {
  return (x << d) | (x >> (32 - d));
}

// JAX threefry2x32, key = (0, 42)  (jax.random.key(42) -> [hi=0, lo=42])
__device__ __forceinline__ void threefry2x32_k42(uint32_t x0, uint32_t x1,
                                                 uint32_t& o0, uint32_t& o1) {
  const uint32_t ks0 = 0u;
  const uint32_t ks1 = 42u;
  const uint32_t ks2 = 0x1BD11BDAu ^ 0u ^ 42u;
  x0 += ks0;
  x1 += ks1;
#define TF_ROUND(r) { x0 += x1; x1 = rotl32(x1, (r)); x1 ^= x0; }
  TF_ROUND(13) TF_ROUND(15) TF_ROUND(26) TF_ROUND(6)
  x0 += ks1; x1 += ks2 + 1u;
  TF_ROUND(17) TF_ROUND(29) TF_ROUND(16) TF_ROUND(24)
  x0 += ks2; x1 += ks0 + 2u;
  TF_ROUND(13) TF_ROUND(15) TF_ROUND(26) TF_ROUND(6)
  x0 += ks0; x1 += ks1 + 3u;
  TF_ROUND(17) TF_ROUND(29) TF_ROUND(16) TF_ROUND(24)
  x0 += ks1; x1 += ks2 + 4u;
  TF_ROUND(13) TF_ROUND(15) TF_ROUND(26) TF_ROUND(6)
  x0 += ks2; x1 += ks0 + 5u;
#undef TF_ROUND
  o0 = x0;
  o1 = x1;
}

// Bit-exact port of Eigen's plog_float (generic_plog, MathFunctionsImpl.h),
// which XLA:CPU's GenerateVF32Log mirrors. Three-way polynomial split
// combined with x^3 (NOT straight Horner), pmadd == hardware FMA on the
// AVX-FMA host, and the exact Eigen tail association:
//   y += e*q1 (mul, add); x -= 0.5*x2; x += y; x += e*q2.
// Valid for positive, finite, normal inputs (all our call sites).
__device__ __forceinline__ float eigen_plogf(float xin) {
#pragma clang fp contract(off)
  // pfrexp: xin = x * 2^e, x in [0.5, 1)
  uint32_t ux = __float_as_uint(xin);
  int e_int = (int)(ux >> 23) - 126;
  float x = __uint_as_float((ux & 0x007fffffu) | 0x3f000000u);
  float e = (float)e_int;
  const float SQRTHF = 0.707106781186547524f;
  bool m = (x < SQRTHF);
  float tmp = m ? x : 0.0f;
  x = x - 1.0f;
  e = e - (m ? 1.0f : 0.0f);
  x = x + tmp;

  float x2 = x * x;
  float x3 = x2 * x;
  // three sub-polynomials (Eigen order)
  float y  = fmaf(7.0376836292e-2f,  x, -1.1514610310e-1f);
  float y1 = fmaf(-1.2420140846e-1f, x,  1.4249322787e-1f);
  float y2 = fmaf(2.0000714765e-1f,  x, -2.4999993993e-1f);
  y  = fmaf(y,  x,  1.1676998740e-1f);
  y1 = fmaf(y1, x, -1.6668057665e-1f);
  y2 = fmaf(y2, x,  3.3333331174e-1f);
  y  = fmaf(y,  x3, y1);
  y  = fmaf(y,  x3, y2);
  y  = y * x3;
  // Eigen tail (separate mul/add, exact association)
  float ey1 = e * -2.12194440e-4f;  // pmul (rounds)
  float t2  = x2 * 0.5f;            // exact
  y = y + ey1;                      // padd
  x = x - t2;                       // psub
  float ey2 = e * 0.693359375f;     // exact
  x = x + y;
  x = x + ey2;
  return x;
}

// Bit-exact port of numpy's SIMD float32 np.log (NPY_COEFF_{P,Q}*_LOGf):
// m in [0.75,1.5), t = m-1, log(m) = (t*P(t))/Q(t), + e*ln2f.
__device__ __forceinline__ float np_logf(float xin) {
#pragma clang fp contract(off)
  uint32_t ux = __float_as_uint(xin);
  int e2 = (int)(ux >> 23) - 127;                                 // [1,2) exp
  float mant = __uint_as_float((ux & 0x007fffffu) | 0x3f800000u); // [1,2)
  if (mant >= 1.5f) { mant = mant * 0.5f; e2 += 1; }              // ->[0.75,1.5)
  float e = (float)e2;
  float t = mant - 1.0f;                                          // exact
  float num = fmaf(2.589979117907922693523e-02f, t, 3.808837741388407920751e-01f);
  num = fmaf(num, t, 1.480000633400055983228e+00f);
  num = fmaf(num, t, 2.112677543073053063722e+00f);
  num = fmaf(num, t, 9.999999999999998702752e-01f);
  num = num * t;                                                  // P0 = 0
  float den = fmaf(5.875095403124574342950e-03f, t, 1.546476374983906719538e-01f);
  den = fmaf(den, t, 9.864942958519418960339e-01f);
  den = fmaf(den, t, 2.453006071784736363091e+00f);
  den = fmaf(den, t, 2.612677543073109236779e+00f);
  den = fmaf(den, t, 1.0f);                                       // Q0 = 1
  float r = num / den;                                            // IEEE f32 div
  return fmaf(e, 0.693147182464599609375f, r);                    // ln2 (f32)
}

// score -> descending-order uint32 key (smaller key == larger score)
__device__ __forceinline__ uint32_t order_key(const float* __restrict__ flows,
                                              int p, uint32_t bits) {
#pragma clang fp contract(off)
  int b = p >> 18;               // p / HW
  int j = p & (HW - 1);
  const float* fb = flows + ((size_t)b << 19);  // b * 2 * HW
  float x = fb[j];
  float y = fb[j + HW];
  float xx = x * x;
  float yy = y * y;
  float ss = xx + yy;
  // correctly-rounded f32 sqrt and division via double round-trip
  float sq = (float)sqrt((double)ss);
  float dist = (float)((double)sq / (double)0.07f);
  // logits: np.log on host (rational SIMD log) — demonstrated inert R2..R5
  float logits = np_logf(dist + 1e-20f);
  // gumbel: jax.random.gumbel on host CPU -> XLA/Eigen plog_float
  float f = __uint_as_float((bits >> 9) | 0x3f800000u) - 1.0f;
  float u = fmaxf(f, 1.17549435e-38f);
  float g = -eigen_plogf(-eigen_plogf(u));
  float s = logits + g;
  uint32_t mm = __float_as_uint(s);
  mm = (mm & 0x80000000u) ? ~mm : (mm | 0x80000000u);  // ascending map
  return ~mm;                                          // descending rank key
}

__global__ void k_compute(const float* __restrict__ flows, uint32_t* __restrict__ d) {
  int p = blockIdx.x * blockDim.x + threadIdx.x;
  // JAX partitionable threefry, 32-bit path:
  //   counts = iota(uint64); ctr = (hi = i>>32 = 0, lo = i); bits = o0 ^ o1
  uint32_t o0, o1;
  threefry2x32_k42(0u, (uint32_t)p, o0, o1);
  d[p] = order_key(flows, p, o0 ^ o1);
}

__global__ void k_init(uint32_t* hist, uint32_t* state, uint32_t* cnt) {
  int t = blockIdx.x * blockDim.x + threadIdx.x;
  if (t < NB * 256) hist[t] = 0u;
  if (t < NB) {
    state[2 * t] = 0u;       // prefix
    state[2 * t + 1] = TOPK; // remaining rank
    cnt[t] = 0u;
  }
}

__global__ void k_hist(const uint32_t* __restrict__ d,
                       const uint32_t* __restrict__ state,
                       uint32_t* __restrict__ hist, int pass) {
  __shared__ uint32_t lh[256];
  lh[threadIdx.x] = 0u;
  __syncthreads();
  int p = blockIdx.x * 256 + threadIdx.x;
  int b = p >> 18;
  uint32_t dv = d[p];
  int shift = 24 - 8 * pass;
  bool ok;
  if (pass == 0) {
    ok = true;
  } else {
    uint32_t pfx = state[2 * b];
    ok = ((dv >> (shift + 8)) == pfx);
  }
  if (ok) atomicAdd(&lh[(dv >> shift) & 0xFFu], 1u);
  __syncthreads();
  uint32_t c = lh[threadIdx.x];
  if (c) atomicAdd(&hist[b * 256 + threadIdx.x], c);
}

__global__ void k_scan(uint32_t* hist, uint32_t* state) {
  int b = blockIdx.x;
  __shared__ uint32_t h[256];
  h[threadIdx.x] = hist[b * 256 + threadIdx.x];
  hist[b * 256 + threadIdx.x] = 0u;  // zero for next pass
  __syncthreads();
  if (threadIdx.x == 0) {
    uint32_t rem = state[2 * b + 1];
    uint32_t pfx = state[2 * b];
    uint32_t cum = 0u;
    int bin = 255;
    for (int i = 0; i < 256; ++i) {
      if (cum + h[i] >= rem) { bin = i; break; }
      cum += h[i];
    }
    state[2 * b] = (pfx << 8) | (uint32_t)bin;
    state[2 * b + 1] = rem - cum;
  }
}

__global__ void k_gather(const uint32_t* __restrict__ d,
                         const uint32_t* __restrict__ state,
                         uint32_t* __restrict__ cnt,
                         unsigned long long* __restrict__ winners) {
  int p = blockIdx.x * 256 + threadIdx.x;
  int b = p >> 18;
  uint32_t dv = d[p];
  uint32_t T = state[2 * b];  // after 4 passes: full 32-bit threshold key
  if (dv <= T) {
    uint32_t pos = atomicAdd(&cnt[b], 1u);
    if (pos < 8192u) {
      winners[(size_t)b * 8192 + pos] =
          ((unsigned long long)dv << 32) | (unsigned long long)(p & (HW - 1));
    }
  }
}

__global__ __launch_bounds__(1024) void k_sort(const uint32_t* __restrict__ cnt,
                                               const unsigned long long* __restrict__ winners,
                                               float* __restrict__ out_idx,
                                               uint8_t* __restrict__ mask) {
  __shared__ unsigned long long s[8192];
  int b = blockIdx.x;
  uint32_t n = cnt[b];
  if (n > 8192u) n = 8192u;
  for (int i = threadIdx.x; i < 8192; i += 1024)
    s[i] = (i < (int)n) ? winners[(size_t)b * 8192 + i] : 0xFFFFFFFFFFFFFFFFull;
  __syncthreads();
  // bitonic sort ascending on (key<<32 | index): score desc, index asc ties
  for (int k = 2; k <= 8192; k <<= 1) {
    for (int j = k >> 1; j > 0; j >>= 1) {
      for (int i = threadIdx.x; i < 8192; i += 1024) {
        int ixj = i ^ j;
        if (ixj > i) {
          bool up = ((i & k) == 0);
          unsigned long long a = s[i];
          unsigned long long c = s[ixj];
          if ((a > c) == up) { s[i] = c; s[ixj] = a; }
        }
      }
      __syncthreads();
    }
  }
  for (int i = threadIdx.x; i < TOPK; i += 1024) {
    unsigned long long v = s[i];
    uint32_t j = (uint32_t)(v & 0xFFFFFFFFull);
    out_idx[(size_t)b * TOPK + i] = (float)j;  // harness reads buffer as f32
    if (j < HW) mask[(size_t)b * HW + j] = 1;
  }
}

__global__ void k_final(const float* __restrict__ flows,
                        const uint8_t* __restrict__ mask,
                        float* __restrict__ out0,
                        float* __restrict__ out_masks) {
  int p = blockIdx.x * 256 + threadIdx.x;
  int b = p >> 18;
  int j = p & (HW - 1);
  float m = mask[p] ? 1.0f : 0.0f;
  const float* fb = flows + ((size_t)b << 19);
  float x = fb[j];
  float y = fb[j + HW];
  size_t base = ((size_t)b * 3) * HW + j;
  out0[base] = m * x;
  out0[base + HW] = m * y;
  out0[base + 2 * HW] = m;
  out_masks[(size_t)b * HW + j] = m;
}

extern "C" void kernel_launch(void* const* d_in, const int* in_sizes, int n_in,
                              void* d_out, int out_size, void* d_ws, size_t ws_size,
                              hipStream_t stream) {
  const float* flows = (const float*)d_in[0];
  float* out = (float*)d_out;
  char* ws = (char*)d_ws;

  uint32_t* d = (uint32_t*)ws;
  uint8_t* mask = (uint8_t*)(ws + 33554432);
  uint32_t* hist = (uint32_t*)(ws + 41943040);
  uint32_t* state = (uint32_t*)(ws + 41975808);
  uint32_t* cnt = (uint32_t*)(ws + 41976064);
  unsigned long long* winners = (unsigned long long*)(ws + 41976192);

  float* out_indices = out + (size_t)NB * 3 * HW;          // 25,165,824
  float* out_masks = out_indices + (size_t)NB * TOPK;      // 25,296,896

  hipMemsetAsync(mask, 0, NTOTAL, stream);
  k_init<<<32, 256, 0, stream>>>(hist, state, cnt);
  k_compute<<<NTOTAL / 256, 256, 0, stream>>>(flows, d);
  for (int pass = 0; pass < 4; ++pass) {
    k_hist<<<NTOTAL / 256, 256, 0, stream>>>(d, state, hist, pass);
    k_scan<<<32, 256, 0, stream>>>(hist, state);
  }
  k_gather<<<NTOTAL / 256, 256, 0, stream>>>(d, state, cnt, winners);
  k_sort<<<32, 1024, 0, stream>>>(cnt, winners, out_indices, mask);
  k_final<<<NTOTAL / 256, 256, 0, stream>>>(flows, mask, out, out_masks);
}

// Round 7
// 421.571 us; speedup vs baseline: 4.6097x; 4.6097x over previous
//
#include <hip/hip_runtime.h>
#include <stdint.h>

#define HW 262144              // 512*512
#define NB 32                  // batch
#define TOPK 4096
#define NTOTAL (NB * HW)       // 8388608
#define GBLK 4096              // elements per block for hist/gather (divides HW)

// ---------------- ws layout (bytes) ----------------
// d:       uint32[NTOTAL]            @ 0          (33,554,432)
// mask:    uint8 [NTOTAL]            @ 33554432   ( 8,388,608)
// hist:    uint32[NB][256]           @ 41943040   (    32,768)
// state:   uint32[NB][2] (pfx, rem)  @ 41975808   (       256)
// cnt:     uint32[NB]                @ 41976064   (       128)
// winners: uint64[NB][8192]          @ 41976192   ( 2,097,152)

__device__ __forceinline__ uint32_t rotl32(uint32_t x, int d) {
  return (x << d) | (x >> (32 - d));
}

// JAX threefry2x32, key = (0, 42)
__device__ __forceinline__ void threefry2x32_k42(uint32_t x0, uint32_t x1,
                                                 uint32_t& o0, uint32_t& o1) {
  const uint32_t ks0 = 0u;
  const uint32_t ks1 = 42u;
  const uint32_t ks2 = 0x1BD11BDAu ^ 0u ^ 42u;
  x0 += ks0;
  x1 += ks1;
#define TF_ROUND(r) { x0 += x1; x1 = rotl32(x1, (r)); x1 ^= x0; }
  TF_ROUND(13) TF_ROUND(15) TF_ROUND(26) TF_ROUND(6)
  x0 += ks1; x1 += ks2 + 1u;
  TF_ROUND(17) TF_ROUND(29) TF_ROUND(16) TF_ROUND(24)
  x0 += ks2; x1 += ks0 + 2u;
  TF_ROUND(13) TF_ROUND(15) TF_ROUND(26) TF_ROUND(6)
  x0 += ks0; x1 += ks1 + 3u;
  TF_ROUND(17) TF_ROUND(29) TF_ROUND(16) TF_ROUND(24)
  x0 += ks1; x1 += ks2 + 4u;
  TF_ROUND(13) TF_ROUND(15) TF_ROUND(26) TF_ROUND(6)
  x0 += ks2; x1 += ks0 + 5u;
#undef TF_ROUND
  o0 = x0;
  o1 = x1;
}

// Bit-exact Eigen plog_float (3-way poly split + Eigen tail association).
// Verified absmax=0 in round 6. DO NOT TOUCH.
__device__ __forceinline__ float eigen_plogf(float xin) {
#pragma clang fp contract(off)
  uint32_t ux = __float_as_uint(xin);
  int e_int = (int)(ux >> 23) - 126;
  float x = __uint_as_float((ux & 0x007fffffu) | 0x3f000000u);
  float e = (float)e_int;
  const float SQRTHF = 0.707106781186547524f;
  bool m = (x < SQRTHF);
  float tmp = m ? x : 0.0f;
  x = x - 1.0f;
  e = e - (m ? 1.0f : 0.0f);
  x = x + tmp;
  float x2 = x * x;
  float x3 = x2 * x;
  float y  = fmaf(7.0376836292e-2f,  x, -1.1514610310e-1f);
  float y1 = fmaf(-1.2420140846e-1f, x,  1.4249322787e-1f);
  float y2 = fmaf(2.0000714765e-1f,  x, -2.4999993993e-1f);
  y  = fmaf(y,  x,  1.1676998740e-1f);
  y1 = fmaf(y1, x, -1.6668057665e-1f);
  y2 = fmaf(y2, x,  3.3333331174e-1f);
  y  = fmaf(y,  x3, y1);
  y  = fmaf(y,  x3, y2);
  y  = y * x3;
  float ey1 = e * -2.12194440e-4f;
  float t2  = x2 * 0.5f;
  y = y + ey1;
  x = x - t2;
  float ey2 = e * 0.693359375f;
  x = x + y;
  x = x + ey2;
  return x;
}

// Bit-exact numpy SIMD f32 np.log (rational). Verified round 6. DO NOT TOUCH.
__device__ __forceinline__ float np_logf(float xin) {
#pragma clang fp contract(off)
  uint32_t ux = __float_as_uint(xin);
  int e2 = (int)(ux >> 23) - 127;
  float mant = __uint_as_float((ux & 0x007fffffu) | 0x3f800000u);
  if (mant >= 1.5f) { mant = mant * 0.5f; e2 += 1; }
  float e = (float)e2;
  float t = mant - 1.0f;
  float num = fmaf(2.589979117907922693523e-02f, t, 3.808837741388407920751e-01f);
  num = fmaf(num, t, 1.480000633400055983228e+00f);
  num = fmaf(num, t, 2.112677543073053063722e+00f);
  num = fmaf(num, t, 9.999999999999998702752e-01f);
  num = num * t;
  float den = fmaf(5.875095403124574342950e-03f, t, 1.546476374983906719538e-01f);
  den = fmaf(den, t, 9.864942958519418960339e-01f);
  den = fmaf(den, t, 2.453006071784736363091e+00f);
  den = fmaf(den, t, 2.612677543073109236779e+00f);
  den = fmaf(den, t, 1.0f);
  float r = num / den;
  return fmaf(e, 0.693147182464599609375f, r);
}

// score -> descending-order uint32 key. Verified round 6. DO NOT TOUCH.
__device__ __forceinline__ uint32_t order_key(const float* __restrict__ flows,
                                              int p, uint32_t bits) {
#pragma clang fp contract(off)
  int b = p >> 18;
  int j = p & (HW - 1);
  const float* fb = flows + ((size_t)b << 19);
  float x = fb[j];
  float y = fb[j + HW];
  float xx = x * x;
  float yy = y * y;
  float ss = xx + yy;
  float sq = (float)sqrt((double)ss);
  float dist = (float)((double)sq / (double)0.07f);
  float logits = np_logf(dist + 1e-20f);
  float f = __uint_as_float((bits >> 9) | 0x3f800000u) - 1.0f;
  float u = fmaxf(f, 1.17549435e-38f);
  float g = -eigen_plogf(-eigen_plogf(u));
  float s = logits + g;
  uint32_t mm = __float_as_uint(s);
  mm = (mm & 0x80000000u) ? ~mm : (mm | 0x80000000u);
  return ~mm;
}

__global__ void k_compute(const float* __restrict__ flows, uint32_t* __restrict__ d) {
  int p = blockIdx.x * blockDim.x + threadIdx.x;
  uint32_t o0, o1;
  threefry2x32_k42(0u, (uint32_t)p, o0, o1);
  d[p] = order_key(flows, p, o0 ^ o1);
}

__global__ void k_init(uint32_t* hist, uint32_t* state, uint32_t* cnt) {
  int t = blockIdx.x * blockDim.x + threadIdx.x;
  if (t < NB * 256) hist[t] = 0u;
  if (t < NB) {
    state[2 * t] = 0u;       // prefix
    state[2 * t + 1] = TOPK; // remaining rank
    cnt[t] = 0u;
  }
}

// G12: LDS-aggregated histogram. 2048 blocks x 256 thr x 16 elems.
__global__ __launch_bounds__(256) void k_hist(const uint32_t* __restrict__ d,
                                              const uint32_t* __restrict__ state,
                                              uint32_t* __restrict__ hist, int pass) {
  __shared__ uint32_t lh[256];
  lh[threadIdx.x] = 0u;
  __syncthreads();
  int blk = blockIdx.x;
  int base = blk * GBLK;
  int b = base >> 18;                 // GBLK divides HW -> single batch/block
  int shift = 24 - 8 * pass;
  uint32_t pfx = (pass == 0) ? 0u : state[2 * b];
  for (int it = 0; it < GBLK / 256; ++it) {
    int p = base + it * 256 + threadIdx.x;
    uint32_t dv = d[p];
    bool ok = (pass == 0) || ((dv >> (shift + 8)) == pfx);
    if (ok) atomicAdd(&lh[(dv >> shift) & 0xFFu], 1u);
  }
  __syncthreads();
  uint32_t c = lh[threadIdx.x];
  if (c) atomicAdd(&hist[b * 256 + threadIdx.x], c);
}

__global__ void k_scan(uint32_t* hist, uint32_t* state) {
  int b = blockIdx.x;
  __shared__ uint32_t h[256];
  h[threadIdx.x] = hist[b * 256 + threadIdx.x];
  hist[b * 256 + threadIdx.x] = 0u;  // zero for next pass
  __syncthreads();
  if (threadIdx.x == 0) {
    uint32_t rem = state[2 * b + 1];
    uint32_t pfx = state[2 * b];
    uint32_t cum = 0u;
    int bin = 255;
    for (int i = 0; i < 256; ++i) {
      if (cum + h[i] >= rem) { bin = i; break; }
      cum += h[i];
    }
    state[2 * b] = (pfx << 8) | (uint32_t)bin;
    state[2 * b + 1] = rem - cum;
  }
}

// G12: LDS-staged winner gather. One global atomic per block (2048 total).
__global__ __launch_bounds__(256) void k_gather(const uint32_t* __restrict__ d,
                                                const uint32_t* __restrict__ state,
                                                uint32_t* __restrict__ cnt,
                                                unsigned long long* __restrict__ winners) {
  __shared__ unsigned long long buf[GBLK];   // 32 KB: worst case all winners
  __shared__ uint32_t lcnt;
  __shared__ uint32_t gbase;
  int blk = blockIdx.x;
  int base = blk * GBLK;
  int b = base >> 18;
  uint32_t T = state[2 * b];
  if (threadIdx.x == 0) lcnt = 0u;
  __syncthreads();
  for (int it = 0; it < GBLK / 256; ++it) {
    int p = base + it * 256 + threadIdx.x;
    uint32_t dv = d[p];
    if (dv <= T) {
      uint32_t pos = atomicAdd(&lcnt, 1u);
      buf[pos] = ((unsigned long long)dv << 32) |
                 (unsigned long long)(p & (HW - 1));
    }
  }
  __syncthreads();
  uint32_t n = lcnt;
  if (threadIdx.x == 0 && n) gbase = atomicAdd(&cnt[b], n);
  __syncthreads();
  for (uint32_t i = threadIdx.x; i < n; i += 256) {
    uint32_t pos = gbase + i;
    if (pos < 8192u) winners[(size_t)b * 8192 + pos] = buf[i];
  }
}

__global__ __launch_bounds__(1024) void k_sort(const uint32_t* __restrict__ cnt,
                                               const unsigned long long* __restrict__ winners,
                                               float* __restrict__ out_idx,
                                               uint8_t* __restrict__ mask) {
  __shared__ unsigned long long s[8192];
  int b = blockIdx.x;
  uint32_t n = cnt[b];
  if (n > 8192u) n = 8192u;
  for (int i = threadIdx.x; i < 8192; i += 1024)
    s[i] = (i < (int)n) ? winners[(size_t)b * 8192 + i] : 0xFFFFFFFFFFFFFFFFull;
  __syncthreads();
  // bitonic sort ascending on (key<<32 | index): score desc, index asc ties
  for (int k = 2; k <= 8192; k <<= 1) {
    for (int j = k >> 1; j > 0; j >>= 1) {
      for (int i = threadIdx.x; i < 8192; i += 1024) {
        int ixj = i ^ j;
        if (ixj > i) {
          bool up = ((i & k) == 0);
          unsigned long long a = s[i];
          unsigned long long c = s[ixj];
          if ((a > c) == up) { s[i] = c; s[ixj] = a; }
        }
      }
      __syncthreads();
    }
  }
  for (int i = threadIdx.x; i < TOPK; i += 1024) {
    unsigned long long v = s[i];
    uint32_t j = (uint32_t)(v & 0xFFFFFFFFull);
    out_idx[(size_t)b * TOPK + i] = (float)j;
    if (j < HW) mask[(size_t)b * HW + j] = 1;
  }
}

__global__ void k_final(const float* __restrict__ flows,
                        const uint8_t* __restrict__ mask,
                        float* __restrict__ out0,
                        float* __restrict__ out_masks) {
  int p = blockIdx.x * 256 + threadIdx.x;
  int b = p >> 18;
  int j = p & (HW - 1);
  float m = mask[p] ? 1.0f : 0.0f;
  const float* fb = flows + ((size_t)b << 19);
  float x = fb[j];
  float y = fb[j + HW];
  size_t base = ((size_t)b * 3) * HW + j;
  out0[base] = m * x;
  out0[base + HW] = m * y;
  out0[base + 2 * HW] = m;
  out_masks[(size_t)b * HW + j] = m;
}

extern "C" void kernel_launch(void* const* d_in, const int* in_sizes, int n_in,
                              void* d_out, int out_size, void* d_ws, size_t ws_size,
                              hipStream_t stream) {
  const float* flows = (const float*)d_in[0];
  float* out = (float*)d_out;
  char* ws = (char*)d_ws;

  uint32_t* d = (uint32_t*)ws;
  uint8_t* mask = (uint8_t*)(ws + 33554432);
  uint32_t* hist = (uint32_t*)(ws + 41943040);
  uint32_t* state = (uint32_t*)(ws + 41975808);
  uint32_t* cnt = (uint32_t*)(ws + 41976064);
  unsigned long long* winners = (unsigned long long*)(ws + 41976192);

  float* out_indices = out + (size_t)NB * 3 * HW;          // 25,165,824
  float* out_masks = out_indices + (size_t)NB * TOPK;      // 25,296,896

  hipMemsetAsync(mask, 0, NTOTAL, stream);
  k_init<<<32, 256, 0, stream>>>(hist, state, cnt);
  k_compute<<<NTOTAL / 256, 256, 0, stream>>>(flows, d);
  for (int pass = 0; pass < 4; ++pass) {
    k_hist<<<NTOTAL / GBLK, 256, 0, stream>>>(d, state, hist, pass);
    k_scan<<<32, 256, 0, stream>>>(hist, state);
  }
  k_gather<<<NTOTAL / GBLK, 256, 0, stream>>>(d, state, cnt, winners);
  k_sort<<<32, 1024, 0, stream>>>(cnt, winners, out_indices, mask);
  k_final<<<NTOTAL / 256, 256, 0, stream>>>(flows, mask, out, out_masks);
}